// Round 5
// baseline (171.457 us; speedup 1.0000x reference)
//
#include <hip/hip_runtime.h>
#include <hip/hip_bf16.h>

// Edge MLP via MFMA, round 5: counting-sort edges by src-bucket to convert
// src-side gather misses into L1 hits (miss-cap/Little's-law bound per r3/r4).
//  Pipeline: hist(16 blk, LDS) -> scan(1 blk) -> scatter -> prep(hbf+W1t) -> main.
//  Main: 4 waves x 32 edges/block, B-frags from padded LDS (STRK=136 -> 2-way
//  conflicts only), gathers from bf16 h-table, scattered store via sorig.
//  Determinism: scatter order within a bin is nondeterministic, but each edge's
//  output value/location is order-independent -> identical d_out every call.

#define NEDGE 600000
#define NNODES 50000
#define DIN 128
#define DH 64
#define NBIN 4096      // bins = src>>4 -> 3125 used
#define BINSH 4
#define HISTB 16
#define STRK 136

typedef __attribute__((ext_vector_type(8))) short bf16x8;
typedef __attribute__((ext_vector_type(4))) float f32x4;
typedef __attribute__((ext_vector_type(4))) unsigned int u32x4;

static __device__ __forceinline__ short f2bf(float f) {
    __hip_bfloat16 hb = __float2bfloat16(f);
    return *reinterpret_cast<short*>(&hb);
}
static __device__ __forceinline__ float bflo(unsigned int w) {
    return __builtin_bit_cast(float, w << 16);
}
static __device__ __forceinline__ float bfhi(unsigned int w) {
    return __builtin_bit_cast(float, w & 0xffff0000u);
}

// ---- K2: per-block LDS histogram of src buckets; writes partials (no pre-zero).
__global__ __launch_bounds__(256) void hist_kernel(
    const int* __restrict__ src, int* __restrict__ bincnt)
{
    __shared__ int lh[NBIN];
    for (int i = threadIdx.x; i < NBIN; i += 256) lh[i] = 0;
    __syncthreads();
    const int chunk = NEDGE / HISTB;                    // 37500
    const int s0 = blockIdx.x * chunk;
    for (int i = s0 + threadIdx.x; i < s0 + chunk; i += 256)
        atomicAdd(&lh[((unsigned)src[i]) >> BINSH], 1);
    __syncthreads();
    for (int i = threadIdx.x; i < NBIN; i += 256)
        bincnt[i * HISTB + blockIdx.x] = lh[i];         // [bin][histblock]
}

// ---- K3: exclusive scan of 4096 bins (sum 16 partials each), 1 block.
__global__ __launch_bounds__(1024) void scan_kernel(
    const int* __restrict__ bincnt, int* __restrict__ cursor)
{
    __shared__ int ts[1024];
    const int t = threadIdx.x;
    int pre[4];
    int s = 0;
#pragma unroll
    for (int j = 0; j < 4; ++j) {
        int bin = t * 4 + j;
        int v = 0;
#pragma unroll
        for (int b = 0; b < HISTB; ++b) v += bincnt[bin * HISTB + b];
        pre[j] = s; s += v;
    }
    ts[t] = s;
    __syncthreads();
    for (int off = 1; off < 1024; off <<= 1) {
        int v = (t >= off) ? ts[t - off] : 0;
        __syncthreads();
        ts[t] += v;
        __syncthreads();
    }
    int excl = (t > 0) ? ts[t - 1] : 0;
#pragma unroll
    for (int j = 0; j < 4; ++j) cursor[t * 4 + j] = excl + pre[j];
}

// ---- K4: scatter edges into bucket-sorted arrays.
__global__ __launch_bounds__(256) void scatter_kernel(
    const int* __restrict__ src, const int* __restrict__ dst,
    int* __restrict__ cursor, int* __restrict__ ssrc,
    int* __restrict__ sdst, int* __restrict__ sorig)
{
    int e = blockIdx.x * 256 + threadIdx.x;
    if (e >= NEDGE) return;
    int s = src[e], d = dst[e];
    int pos = atomicAdd(&cursor[((unsigned)s) >> BINSH], 1);
    ssrc[pos] = s; sdst[pos] = d; sorig[pos] = e;
}

// ---- K5: fused prep: h -> bf16 table (blocks < wofs), W1 -> W1^T bf16 (rest).
__global__ __launch_bounds__(256) void prep_kernel(
    const float* __restrict__ h, const float* __restrict__ W1,
    unsigned short* __restrict__ hbf, unsigned short* __restrict__ w1t, int wofs)
{
    int b = blockIdx.x;
    if (b < wofs) {
        int i = (b * 256 + threadIdx.x) * 4;
        f32x4 v = *reinterpret_cast<const f32x4*>(h + i);
        ushort4 o;
        o.x = (unsigned short)f2bf(v[0]);
        o.y = (unsigned short)f2bf(v[1]);
        o.z = (unsigned short)f2bf(v[2]);
        o.w = (unsigned short)f2bf(v[3]);
        *reinterpret_cast<ushort4*>(hbf + i) = o;
    } else {
        int j = ((b - wofs) * 256 + threadIdx.x) * 4;
        f32x4 w = *reinterpret_cast<const f32x4*>(W1 + j);
        int k = j >> 6, c = j & 63;
#pragma unroll
        for (int q = 0; q < 4; ++q)
            w1t[(c + q) * DIN + k] = (unsigned short)f2bf(w[q]);
    }
}

// ---- K6: main. MODE 0 = sorted (indirect store), 1 = unsorted identity.
template<int MODE>
__global__ __launch_bounds__(256, 4) void mlp_main(
    const unsigned short* __restrict__ hbf,
    const unsigned short* __restrict__ w1t,
    const int* __restrict__ ssrc, const int* __restrict__ sdst,
    const int* __restrict__ sorig,
    const float* __restrict__ b1, const float* __restrict__ W2,
    const float* __restrict__ b2, float* __restrict__ out)
{
    __shared__ unsigned short Blds[DH * STRK];
#pragma unroll
    for (int j = 0; j < 4; ++j) {
        int i = (threadIdx.x + j * 256) * 8;            // 0..8191, same row per 8
        int r = i >> 7, c = i & 127;
        const ushort4* ps = reinterpret_cast<const ushort4*>(w1t + i);
        ushort4 v0 = ps[0], v1 = ps[1];
        *reinterpret_cast<ushort4*>(&Blds[r * STRK + c]) = v0;
        *reinterpret_cast<ushort4*>(&Blds[r * STRK + c + 4]) = v1;
    }
    __syncthreads();

    const int tid = threadIdx.x;
    const int l = tid & 63;
    const int lr = l & 15;       // edge row (A) / hid col (B,C)
    const int g = l >> 4;        // k-group
    const unsigned kg = (unsigned)(g * 8);
    const int bpos = blockIdx.x * 128 + (tid >> 6) * 32;

    float bv[4]; float2 w2v[4];
#pragma unroll
    for (int n = 0; n < 4; ++n) {
        bv[n] = b1[n * 16 + lr];
        w2v[n] = *reinterpret_cast<const float2*>(W2 + (n * 16 + lr) * 2);
    }
    const float bb0 = b2[0], bb1 = b2[1];

#pragma unroll
    for (int m = 0; m < 2; ++m) {
        int p = bpos + m * 16 + lr;
        if (p >= NEDGE) p = NEDGE - 1;                  // tail clamp (last block)
        const unsigned sa = (unsigned)ssrc[p] * (unsigned)DIN;
        const unsigned da = (unsigned)sdst[p] * (unsigned)DIN;

        u32x4 S[4], D[4];
#pragma unroll
        for (int ks = 0; ks < 4; ++ks) {
            S[ks] = *reinterpret_cast<const u32x4*>(hbf + sa + ks * 32 + kg);
            D[ks] = *reinterpret_cast<const u32x4*>(hbf + da + ks * 32 + kg);
        }

        f32x4 acc[4];
#pragma unroll
        for (int n = 0; n < 4; ++n) acc[n] = (f32x4){bv[n], bv[n], bv[n], bv[n]};

#pragma unroll
        for (int ks = 0; ks < 4; ++ks) {
            bf16x8 A;
#pragma unroll
            for (int w = 0; w < 4; ++w) {
                A[2 * w]     = f2bf(bflo(S[ks][w]) * bflo(D[ks][w]));
                A[2 * w + 1] = f2bf(bfhi(S[ks][w]) * bfhi(D[ks][w]));
            }
#pragma unroll
            for (int n = 0; n < 4; ++n) {
                bf16x8 Bf = *reinterpret_cast<const bf16x8*>(
                    &Blds[(n * 16 + lr) * STRK + ks * 32 + kg]);
                acc[n] = __builtin_amdgcn_mfma_f32_16x16x32_bf16(A, Bf, acc[n], 0, 0, 0);
            }
        }

        // epilogue: relu + [64]->[2], 16-lane butterfly
        float o0 = 0.f, o1 = 0.f;
#pragma unroll
        for (int r = 0; r < 4; ++r) {
            float p0 = 0.f, p1 = 0.f;
#pragma unroll
            for (int n = 0; n < 4; ++n) {
                float v = fmaxf(acc[n][r], 0.f);
                p0 = fmaf(v, w2v[n].x, p0);
                p1 = fmaf(v, w2v[n].y, p1);
            }
#pragma unroll
            for (int sh = 1; sh < 16; sh <<= 1) {
                p0 += __shfl_xor(p0, sh, 64);
                p1 += __shfl_xor(p1, sh, 64);
            }
            if (lr == r) { o0 = p0; o1 = p1; }
        }
        int epos = bpos + m * 16 + g * 4 + lr;          // C row = g*4 + reg
        if (lr < 4 && epos < NEDGE) {
            int oe = (MODE == 0) ? sorig[epos] : epos;
            float2 ov = make_float2(o0 + bb0, o1 + bb1);
            *reinterpret_cast<float2*>(out + (size_t)oe * 2) = ov;
        }
    }
}

// ---- tier-3 fallback: fp32 gather, global W1t (round-4 proven shape) ----
__global__ __launch_bounds__(256) void mlp_f32_fallback(
    const float* __restrict__ hf, const unsigned short* __restrict__ w1t,
    const float* __restrict__ b1, const float* __restrict__ W2,
    const float* __restrict__ b2, const int* __restrict__ src,
    const int* __restrict__ dst, float* __restrict__ out)
{
    const int tid = threadIdx.x;
    const int l = tid & 63, lr = l & 15, g = l >> 4;
    const unsigned kg = (unsigned)(g * 8);
    const int wbase = blockIdx.x * 64 + (tid >> 6) * 16;
    const unsigned e = (unsigned)(wbase + lr);
    const unsigned sa = (unsigned)src[e] * (unsigned)DIN;
    const unsigned da = (unsigned)dst[e] * (unsigned)DIN;
    f32x4 acc[4];
#pragma unroll
    for (int n = 0; n < 4; ++n) {
        float bvv = b1[n * 16 + lr];
        acc[n] = (f32x4){bvv, bvv, bvv, bvv};
    }
#pragma unroll
    for (int ks = 0; ks < 4; ++ks) {
        const float* ps = hf + sa + ks * 128 + g * 32;
        const float* pd = hf + da + ks * 128 + g * 32;
        f32x4 s0 = *reinterpret_cast<const f32x4*>(ps);
        f32x4 s1 = *reinterpret_cast<const f32x4*>(ps + 4);
        f32x4 d0 = *reinterpret_cast<const f32x4*>(pd);
        f32x4 d1 = *reinterpret_cast<const f32x4*>(pd + 4);
        bf16x8 A, B[4];
#pragma unroll
        for (int n = 0; n < 4; ++n)
            B[n] = *reinterpret_cast<const bf16x8*>(w1t + (n * 16 + lr) * DIN + ks * 32 + kg);
#pragma unroll
        for (int q = 0; q < 4; ++q) {
            A[q]     = f2bf(s0[q] * d0[q]);
            A[q + 4] = f2bf(s1[q] * d1[q]);
        }
#pragma unroll
        for (int n = 0; n < 4; ++n)
            acc[n] = __builtin_amdgcn_mfma_f32_16x16x32_bf16(A, B[n], acc[n], 0, 0, 0);
    }
    float2 w2v[4];
#pragma unroll
    for (int n = 0; n < 4; ++n)
        w2v[n] = *reinterpret_cast<const float2*>(W2 + (n * 16 + lr) * 2);
    const float bb0 = b2[0], bb1 = b2[1];
    float o0 = 0.f, o1 = 0.f;
#pragma unroll
    for (int r = 0; r < 4; ++r) {
        float p0 = 0.f, p1 = 0.f;
#pragma unroll
        for (int n = 0; n < 4; ++n) {
            float v = fmaxf(acc[n][r], 0.f);
            p0 = fmaf(v, w2v[n].x, p0);
            p1 = fmaf(v, w2v[n].y, p1);
        }
#pragma unroll
        for (int sh = 1; sh < 16; sh <<= 1) {
            p0 += __shfl_xor(p0, sh, 64);
            p1 += __shfl_xor(p1, sh, 64);
        }
        if (lr == r) { o0 = p0; o1 = p1; }
    }
    if (lr < 4) {
        int edge = wbase + g * 4 + lr;
        float2 ov = make_float2(o0 + bb0, o1 + bb1);
        *reinterpret_cast<float2*>(out + (size_t)edge * 2) = ov;
    }
}

extern "C" void kernel_launch(void* const* d_in, const int* in_sizes, int n_in,
                              void* d_out, int out_size, void* d_ws, size_t ws_size,
                              hipStream_t stream) {
    const float* h  = (const float*)d_in[0];
    const float* W1 = (const float*)d_in[1];
    const float* b1 = (const float*)d_in[2];
    const float* W2 = (const float*)d_in[3];
    const float* b2 = (const float*)d_in[4];
    const int* src  = (const int*)d_in[5];
    const int* dst  = (const int*)d_in[6];
    float* out = (float*)d_out;

    // ws layout (bytes)
    const size_t OFF_HBF  = 0;                                  // 12,800,000
    const size_t OFF_W1T  = 12800000;                           // 16,384
    const size_t OFF_BCNT = 12816384;                           // 4096*16*4 = 262,144
    const size_t OFF_CUR  = 13078528;                           // 16,384
    const size_t OFF_SSRC = 13094912;                           // 2,400,000
    const size_t OFF_SDST = 15494912;                           // 2,400,000
    const size_t OFF_SORG = 17894912;                           // 2,400,000
    const size_t NEED_FULL = 20294912;
    const size_t NEED_BF   = OFF_BCNT;                          // hbf + w1t only
    const size_t NEED_MIN  = 16384;

    char* ws = (char*)d_ws;
    const int HB = (NNODES * DIN) / (256 * 4);   // 6250
    const int WB = (DIN * DH) / (256 * 4);       // 8
    const int MAINB = (NEDGE + 127) / 128;       // 4688

    if (ws_size >= NEED_FULL) {
        unsigned short* hbf = (unsigned short*)(ws + OFF_HBF);
        unsigned short* w1t = (unsigned short*)(ws + OFF_W1T);
        int* bcnt  = (int*)(ws + OFF_BCNT);
        int* cur   = (int*)(ws + OFF_CUR);
        int* ssrc  = (int*)(ws + OFF_SSRC);
        int* sdst  = (int*)(ws + OFF_SDST);
        int* sorig = (int*)(ws + OFF_SORG);

        hist_kernel<<<HISTB, 256, 0, stream>>>(src, bcnt);
        scan_kernel<<<1, 1024, 0, stream>>>(bcnt, cur);
        scatter_kernel<<<(NEDGE + 255) / 256, 256, 0, stream>>>(src, dst, cur, ssrc, sdst, sorig);
        prep_kernel<<<HB + WB, 256, 0, stream>>>(h, W1, hbf, w1t, HB);
        mlp_main<0><<<MAINB, 256, 0, stream>>>(hbf, w1t, ssrc, sdst, sorig, b1, W2, b2, out);
    } else if (ws_size >= NEED_BF) {
        unsigned short* hbf = (unsigned short*)(ws + OFF_HBF);
        unsigned short* w1t = (unsigned short*)(ws + OFF_W1T);
        prep_kernel<<<HB + WB, 256, 0, stream>>>(h, W1, hbf, w1t, HB);
        mlp_main<1><<<MAINB, 256, 0, stream>>>(hbf, w1t, src, dst, nullptr, b1, W2, b2, out);
    } else if (ws_size >= NEED_MIN) {
        unsigned short* w1t = (unsigned short*)ws;
        prep_kernel<<<WB, 256, 0, stream>>>(h, W1, nullptr, w1t, 0);
        mlp_f32_fallback<<<NEDGE / 64, 256, 0, stream>>>(h, w1t, b1, W2, b2, src, dst, out);
    }
}